// Round 1
// 1388.438 us; speedup vs baseline: 2.4214x; 2.4214x over previous
//
#include <hip/hip_runtime.h>

// InternLM2VE decoder layer, MI355X gfx950.
// R4: MFMA flash attention replaces the scalar attn_k (was 2343 us / 70% of
// total, MfmaUtil=0). Everything else unchanged from R3.
// H=2048, NH=16, NKV=8, HD=128, S=2048, FF=8192, B=1.
// d_out (f32) = [ out (2048x2048) | residual (2048x2048) ].

typedef __bf16 bf16_t;
typedef __bf16 bf16x8 __attribute__((ext_vector_type(8)));
typedef float f32x4 __attribute__((ext_vector_type(4)));

// ---------------------------------------------------------------------------
// Tiled transpose + cast f32->bf16: Wt[row_off+n][k] = W[k][n].
// ---------------------------------------------------------------------------
__global__ __launch_bounds__(256) void transpose_k(const float* __restrict__ W,
                                                   bf16_t* __restrict__ Wt,
                                                   int K, int N, int row_off) {
  __shared__ bf16_t tile[32][34];  // stride 68B: no pow-2 bank aliasing
  const int tx = threadIdx.x & 31, ty = threadIdx.x >> 5;
  const int n0 = blockIdx.x * 32, k0 = blockIdx.y * 32;
#pragma unroll
  for (int i = 0; i < 4; i++)
    tile[ty + 8 * i][tx] = (bf16_t)W[(size_t)(k0 + ty + 8 * i) * N + n0 + tx];
  __syncthreads();
#pragma unroll
  for (int i = 0; i < 4; i++)
    Wt[(size_t)(row_off + n0 + ty + 8 * i) * K + k0 + tx] = tile[tx][ty + 8 * i];
}

// ---------------------------------------------------------------------------
// bf16 -> bf16 tiled transpose: out[c][r] = in[r][c].  Used to pre-transpose
// the V slice of qkvb ([s][d], ld 4096) into vt [1024 d][2048 s].
// ---------------------------------------------------------------------------
__global__ __launch_bounds__(256) void transpose_bf16_k(
    const bf16_t* __restrict__ in, int ldin, bf16_t* __restrict__ out, int ldout) {
  __shared__ bf16_t tile[32][34];
  const int tx = threadIdx.x & 31, ty = threadIdx.x >> 5;
  const int c0 = blockIdx.x * 32, r0 = blockIdx.y * 32;
#pragma unroll
  for (int i = 0; i < 4; i++)
    tile[ty + 8 * i][tx] = in[(size_t)(r0 + ty + 8 * i) * ldin + c0 + tx];
  __syncthreads();
#pragma unroll
  for (int i = 0; i < 4; i++)
    out[(size_t)(c0 + ty + 8 * i) * ldout + r0 + tx] = tile[tx][ty + 8 * i];
}

// ---------------------------------------------------------------------------
// RMSNorm row: y = bf16( x * rsqrt(mean(x^2)+eps) * w )   (f32 in, bf16 out)
// ---------------------------------------------------------------------------
__global__ __launch_bounds__(256) void rmsnorm_k(const float* __restrict__ x,
                                                 const float* __restrict__ w,
                                                 bf16_t* __restrict__ y) {
  const int row = blockIdx.x, t = threadIdx.x;
  __shared__ float red[256];
  float vals[8];
  float ss = 0.f;
  const float* xr = x + (size_t)row * 2048;
#pragma unroll
  for (int i = 0; i < 8; i++) {
    float v = xr[t + 256 * i];
    vals[i] = v;
    ss += v * v;
  }
  red[t] = ss;
  __syncthreads();
  for (int s = 128; s > 0; s >>= 1) {
    if (t < s) red[t] += red[t + s];
    __syncthreads();
  }
  const float scale = rsqrtf(red[0] * (1.f / 2048.f) + 1e-6f);
  bf16_t* yr = y + (size_t)row * 2048;
#pragma unroll
  for (int i = 0; i < 8; i++)
    yr[t + 256 * i] = (bf16_t)(vals[i] * scale * w[t + 256 * i]);
}

// ---------------------------------------------------------------------------
// RoPE in-place on bf16 qkv buffer (row = 4096: q[16*128] | k[8*128] | v).
// grid (S, 24): heads 0..15 = q, 16..23 = k (offset head*128 covers both).
// ---------------------------------------------------------------------------
__global__ __launch_bounds__(128) void rope_k(bf16_t* __restrict__ qkv,
                                              const float* __restrict__ cosb,
                                              const float* __restrict__ sinb) {
  const int s = blockIdx.x, head = blockIdx.y, d = threadIdx.x;
  bf16_t* p = qkv + (size_t)s * 4096 + head * 128;
  const float x = (float)p[d];
  const float partner = (float)p[d ^ 64];
  const float rot = (d < 64) ? -partner : partner;
  const float c = cosb[s * 128 + d], sn = sinb[s * 128 + d];
  __syncthreads();  // head is block-uniform; all reads before in-place writes
  p[d] = (bf16_t)(x * c + rot * sn);
}

// ---------------------------------------------------------------------------
// MFMA flash attention, causal GQA.  Grid (S/64 = 32 q-tiles, NH = 16).
// 256 threads = 4 waves; wave w owns q rows [q0+16w, q0+16w+16).
// Per 64-wide K-block: stage K (64x128) and Vt (128x64) in LDS, QK^T via
// 16x16x32 bf16 MFMA, wave-parallel online softmax (shfl_xor over the
// 16-lane C-layout groups), P through per-wave LDS scratch to re-fragment,
// PV via 16 more MFMAs into a 16x128 f32 accumulator.
// All LDS strides padded so 16-lane fragment reads spread across banks.
// ---------------------------------------------------------------------------
__global__ __launch_bounds__(256) void attn_mfma_k(
    const bf16_t* __restrict__ qkv,  // [S][4096]: q | k (roped) | v
    const bf16_t* __restrict__ vt,   // [1024][2048]: V transposed (d-major)
    bf16_t* __restrict__ ob) {       // [S][2048]
  __shared__ __align__(16) bf16_t Ks[64][136];   // k x c  (pad 128->136)
  __shared__ __align__(16) bf16_t Vs[128][72];   // d x k  (pad 64->72)
  __shared__ __align__(16) bf16_t Ps[4][16][72]; // per-wave P scratch

  const int t = threadIdx.x;
  const int wid = t >> 6, lane = t & 63;
  const int lr = lane & 15, lg = lane >> 4;
  const int h = blockIdx.y, kvh = h >> 1;
  // heavy q-tiles first (in-order dispatch -> better tail balance)
  const int qt = (int)gridDim.x - 1 - (int)blockIdx.x;
  const int q0 = qt * 64;
  const int nkb = qt + 1;
  const int qrow_base = q0 + wid * 16;

  // Q fragment: lane holds Q[lr][lg*8 + 32*cs + j], j=0..7
  bf16x8 qf[4];
#pragma unroll
  for (int cs = 0; cs < 4; ++cs)
    qf[cs] = *(const bf16x8*)(qkv + (size_t)(qrow_base + lr) * 4096 + h * 128 +
                              lg * 8 + 32 * cs);

  f32x4 acc[8];
#pragma unroll
  for (int dt = 0; dt < 8; ++dt) acc[dt] = f32x4{0.f, 0.f, 0.f, 0.f};
  float m_run[4] = {-1e30f, -1e30f, -1e30f, -1e30f};
  float l_run[4] = {0.f, 0.f, 0.f, 0.f};

  const float SCALE = 0.08838834764831845f;  // 1/sqrt(128)

  for (int kb = 0; kb < nkb; ++kb) {
    const int k0 = kb * 64;
    __syncthreads();  // previous iteration's fragment reads complete
    // stage K tile: 64 rows x 128 c, 1024 bf16x8 vectors, 4 per thread
#pragma unroll
    for (int i = 0; i < 4; ++i) {
      const int v = t + 256 * i;
      const int kr = v >> 4, c = (v & 15) * 8;
      *(bf16x8*)&Ks[kr][c] =
          *(const bf16x8*)(qkv + (size_t)(k0 + kr) * 4096 + 2048 + kvh * 128 + c);
    }
    // stage Vt tile: 128 d-rows x 64 k, from pre-transposed vt (coalesced)
#pragma unroll
    for (int i = 0; i < 4; ++i) {
      const int v = t + 256 * i;
      const int d = v >> 3, kk = (v & 7) * 8;
      *(bf16x8*)&Vs[d][kk] =
          *(const bf16x8*)(vt + (size_t)(kvh * 128 + d) * 2048 + k0 + kk);
    }
    __syncthreads();

    // QK^T: S[q][k] tile 16x64; D layout: lane's sv[t4][r] = S[4*lg+r][16*t4+lr]
    f32x4 sv[4];
#pragma unroll
    for (int t4 = 0; t4 < 4; ++t4) sv[t4] = f32x4{0.f, 0.f, 0.f, 0.f};
#pragma unroll
    for (int cs = 0; cs < 4; ++cs) {
#pragma unroll
      for (int t4 = 0; t4 < 4; ++t4) {
        const bf16x8 kf = *(const bf16x8*)&Ks[16 * t4 + lr][lg * 8 + 32 * cs];
        sv[t4] = __builtin_amdgcn_mfma_f32_16x16x32_bf16(qf[cs], kf, sv[t4], 0, 0, 0);
      }
    }

    // scale + causal mask (only final k-block triggers)
    const bool need_mask = (k0 + 63) > qrow_base;
#pragma unroll
    for (int t4 = 0; t4 < 4; ++t4) {
#pragma unroll
      for (int r = 0; r < 4; ++r) {
        float x = sv[t4][r] * SCALE;
        if (need_mask && (k0 + 16 * t4 + lr) > (qrow_base + 4 * lg + r)) x = -1e30f;
        sv[t4][r] = x;
      }
    }

    // online softmax, per q-row r (row owned by the 16 lanes sharing lg)
#pragma unroll
    for (int r = 0; r < 4; ++r) {
      float mx = fmaxf(fmaxf(sv[0][r], sv[1][r]), fmaxf(sv[2][r], sv[3][r]));
      mx = fmaxf(mx, __shfl_xor(mx, 1));
      mx = fmaxf(mx, __shfl_xor(mx, 2));
      mx = fmaxf(mx, __shfl_xor(mx, 4));
      mx = fmaxf(mx, __shfl_xor(mx, 8));
      const float mnew = fmaxf(m_run[r], mx);
      const float corr = __expf(m_run[r] - mnew);
      m_run[r] = mnew;
      float ls = 0.f;
#pragma unroll
      for (int t4 = 0; t4 < 4; ++t4) {
        const float p = __expf(sv[t4][r] - mnew);
        ls += p;
        Ps[wid][4 * lg + r][16 * t4 + lr] = (bf16_t)p;
      }
      ls += __shfl_xor(ls, 1);
      ls += __shfl_xor(ls, 2);
      ls += __shfl_xor(ls, 4);
      ls += __shfl_xor(ls, 8);
      l_run[r] = l_run[r] * corr + ls;
#pragma unroll
      for (int dt = 0; dt < 8; ++dt) acc[dt][r] *= corr;
    }

    // PV: O[q][d] += P[q][k] V[k][d].  A-frag re-read from Ps (wave-private,
    // compiler orders the intra-wave LDS write->read).
#pragma unroll
    for (int ks = 0; ks < 2; ++ks) {
      const bf16x8 pa = *(const bf16x8*)&Ps[wid][lr][lg * 8 + 32 * ks];
#pragma unroll
      for (int dt = 0; dt < 8; ++dt) {
        const bf16x8 vf = *(const bf16x8*)&Vs[16 * dt + lr][lg * 8 + 32 * ks];
        acc[dt] = __builtin_amdgcn_mfma_f32_16x16x32_bf16(pa, vf, acc[dt], 0, 0, 0);
      }
    }
  }

  // epilogue: normalize and store; lane's acc[dt][r] = O[4*lg+r][16*dt+lr]
#pragma unroll
  for (int r = 0; r < 4; ++r) {
    const float inv = 1.f / l_run[r];
    const size_t row = (size_t)(qrow_base + 4 * lg + r) * 2048 + h * 128;
#pragma unroll
    for (int dt = 0; dt < 8; ++dt)
      ob[row + 16 * dt + lr] = (bf16_t)(acc[dt][r] * inv);
  }
}

// ---------------------------------------------------------------------------
// bf16 MFMA GEMM: C[M,N] = A[M,K] @ Bt[N,K]^T, 128x128 tile, BK=32, 4 waves.
// Explicit bf16x8 load -> ds_write staging; 16B-chunk XOR bank swizzle.
// A rows gathered via a_idx; C rows scattered via c_idx (both optional).
// mode 0: Cf = acc                        [down proj -> f32 out]
// mode 1: Cf = acc + Rf                   [o-proj + residual, f32]
// mode 2: Cb = bf16(silu(Gb) * acc)       [SwiGLU up fuse]
// mode 3: Cb = bf16(acc)                  [QKV, gate]
// ---------------------------------------------------------------------------
__global__ __launch_bounds__(256) void gemm_bt(
    const bf16_t* __restrict__ A, int lda, const int* __restrict__ a_idx,
    const bf16_t* __restrict__ Bt, int K,
    float* __restrict__ Cf, bf16_t* __restrict__ Cb,
    const int* __restrict__ c_idx, int ldc, int mode,
    const bf16_t* __restrict__ Gb, const float* __restrict__ Rf) {
  __shared__ __align__(16) bf16_t As[128 * 32];
  __shared__ __align__(16) bf16_t Bs[128 * 32];
  __shared__ int arows[128];

  const int t = threadIdx.x;
  const int row0 = blockIdx.y * 128, col0 = blockIdx.x * 128;

  if (t < 128) arows[t] = a_idx ? a_idx[row0 + t] : (row0 + t);
  __syncthreads();

  // 512 16B segments per 128x32 tile; seg = p*256+t; m=seg>>2; LDS slot
  // c=seg&3 holds global k-chunk q = c ^ ((m>>1)&3)   (bank swizzle)
  const int sm0 = t >> 2;
  const int sq0 = (((t & 3) ^ ((sm0 >> 1) & 3)) << 3);
  const int sm1 = (t + 256) >> 2;
  const int sq1 = ((((t + 256) & 3) ^ ((sm1 >> 1) & 3)) << 3);

  const bf16_t* gA0 = A + (size_t)arows[sm0] * lda + sq0;
  const bf16_t* gA1 = A + (size_t)arows[sm1] * lda + sq1;
  const bf16_t* gB0 = Bt + (size_t)(col0 + sm0) * K + sq0;
  const bf16_t* gB1 = Bt + (size_t)(col0 + sm1) * K + sq1;
  bf16x8* lA0 = (bf16x8*)(As + t * 8);
  bf16x8* lA1 = (bf16x8*)(As + (t + 256) * 8);
  bf16x8* lB0 = (bf16x8*)(Bs + t * 8);
  bf16x8* lB1 = (bf16x8*)(Bs + (t + 256) * 8);

  const int wid = t >> 6, lane = t & 63;
  const int wm = (wid & 1) << 6, wn = (wid >> 1) << 6;
  const int lrow = lane & 15, lq = lane >> 4;

  int a_off[4], b_off[4];
#pragma unroll
  for (int i = 0; i < 4; i++) {
    const int m = wm + i * 16 + lrow;
    a_off[i] = m * 64 + ((lq ^ ((m >> 1) & 3)) << 4);  // bytes
    const int n = wn + i * 16 + lrow;
    b_off[i] = n * 64 + ((lq ^ ((n >> 1) & 3)) << 4);
  }

  f32x4 acc[4][4];
#pragma unroll
  for (int i = 0; i < 4; i++)
#pragma unroll
    for (int j = 0; j < 4; j++) acc[i][j] = f32x4{0.f, 0.f, 0.f, 0.f};

  for (int k0 = 0; k0 < K; k0 += 32) {
    const bf16x8 ra0 = *(const bf16x8*)(gA0 + k0);
    const bf16x8 ra1 = *(const bf16x8*)(gA1 + k0);
    const bf16x8 rb0 = *(const bf16x8*)(gB0 + k0);
    const bf16x8 rb1 = *(const bf16x8*)(gB1 + k0);
    __syncthreads();  // prior iteration's fragment reads complete
    *lA0 = ra0;
    *lA1 = ra1;
    *lB0 = rb0;
    *lB1 = rb1;
    __syncthreads();  // staging visible
    bf16x8 af[4], bfr[4];
#pragma unroll
    for (int i = 0; i < 4; i++)
      af[i] = *(const bf16x8*)((const char*)As + a_off[i]);
#pragma unroll
    for (int i = 0; i < 4; i++)
      bfr[i] = *(const bf16x8*)((const char*)Bs + b_off[i]);
#pragma unroll
    for (int i = 0; i < 4; i++)
#pragma unroll
      for (int j = 0; j < 4; j++)
        acc[i][j] =
            __builtin_amdgcn_mfma_f32_16x16x32_bf16(af[i], bfr[j], acc[i][j], 0, 0, 0);
  }

#pragma unroll
  for (int i = 0; i < 4; i++) {
#pragma unroll
    for (int r = 0; r < 4; r++) {
      const int gm = row0 + wm + i * 16 + lq * 4 + r;  // C/D: row=(lane>>4)*4+r
      const int crow = c_idx ? c_idx[gm] : gm;
      const size_t base = (size_t)crow * ldc;
#pragma unroll
      for (int j = 0; j < 4; j++) {
        const int col = col0 + wn + j * 16 + lrow;  // C/D: col=lane&15
        float v = acc[i][j][r];
        if (mode == 0) {
          Cf[base + col] = v;
        } else if (mode == 1) {
          Cf[base + col] = v + Rf[base + col];
        } else if (mode == 2) {
          const float g = (float)Gb[base + col];
          Cb[base + col] = (bf16_t)(v * g / (1.f + __expf(-g)));
        } else {
          Cb[base + col] = (bf16_t)v;
        }
      }
    }
  }
}

// ---------------------------------------------------------------------------
extern "C" void kernel_launch(void* const* d_in, const int* in_sizes, int n_in,
                              void* d_out, int out_size, void* d_ws, size_t ws_size,
                              hipStream_t stream) {
  const float* hidden = (const float*)d_in[0];
  const float* cosb = (const float*)d_in[1];
  const float* sinb = (const float*)d_in[2];
  const float* wq = (const float*)d_in[3];
  const float* wk = (const float*)d_in[4];
  const float* wv = (const float*)d_in[5];
  const float* wo = (const float*)d_in[6];
  const float* w1 = (const float*)d_in[7];
  const float* w3 = (const float*)d_in[8];
  const float* w2 = (const float*)d_in[9];
  const float* v1 = (const float*)d_in[10];
  const float* v3 = (const float*)d_in[11];
  const float* v2 = (const float*)d_in[12];
  const float* anw = (const float*)d_in[13];
  const float* fnw = (const float*)d_in[14];
  const int* vidx = (const int*)d_in[15];
  const int* tidx = (const int*)d_in[16];

  float* out0 = (float*)d_out;                // MLP output [2048][2048] f32
  float* outr = out0 + (size_t)2048 * 2048;   // residual   [2048][2048] f32

  // ws layout (72 MB), all bf16 intermediates; offsets in MB
  char* wsb = (char*)d_ws;
  const size_t MB = 1024 * 1024;
  bf16_t* qkvb = (bf16_t*)(wsb + 0 * MB);    // [0,16): QKV out, q/k roped in place
  bf16_t* vt = (bf16_t*)(wsb + 16 * MB);     // [16,20): V transposed [1024][2048]
  bf16_t* attnb = (bf16_t*)(wsb + 24 * MB);  // [24,32)
  bf16_t* hn = (bf16_t*)(wsb + 32 * MB);     // [32,40): norm out (attn, then ffn)
  bf16_t* g = (bf16_t*)(wsb + 0 * MB);       // [0,16): gate (qkvb dead)
  bf16_t* act = (bf16_t*)(wsb + 16 * MB);    // [16,32): silu*up (vt/attnb dead)
  bf16_t* bufT = (bf16_t*)(wsb + 40 * MB);   // [40,72): transposed bf16 weights

  // --- attention block ---
  transpose_k<<<dim3(64, 64), 256, 0, stream>>>(wq, bufT, 2048, 2048, 0);
  transpose_k<<<dim3(32, 64), 256, 0, stream>>>(wk, bufT, 2048, 1024, 2048);
  transpose_k<<<dim3(32, 64), 256, 0, stream>>>(wv, bufT, 2048, 1024, 3072);
  rmsnorm_k<<<2048, 256, 0, stream>>>(hidden, anw, hn);
  gemm_bt<<<dim3(32, 16), 256, 0, stream>>>(hn, 2048, nullptr, bufT, 2048, nullptr,
                                            qkvb, nullptr, 4096, 3, nullptr, nullptr);
  rope_k<<<dim3(2048, 24), 128, 0, stream>>>(qkvb, cosb, sinb);
  transpose_bf16_k<<<dim3(32, 64), 256, 0, stream>>>(qkvb + 3072, 4096, vt, 2048);
  attn_mfma_k<<<dim3(32, 16), 256, 0, stream>>>(qkvb, vt, attnb);
  transpose_k<<<dim3(64, 64), 256, 0, stream>>>(wo, bufT, 2048, 2048, 0);
  gemm_bt<<<dim3(16, 16), 256, 0, stream>>>(attnb, 2048, nullptr, bufT, 2048, outr,
                                            nullptr, nullptr, 2048, 1, nullptr, hidden);
  // --- FFN block (residual re-read f32 from d_out; vision rows, then text) ---
  rmsnorm_k<<<2048, 256, 0, stream>>>(outr, fnw, hn);
  const float* Wg[2] = {v1, w1};
  const float* Wu[2] = {v3, w3};
  const float* Wd[2] = {v2, w2};
  const int* idx[2] = {vidx, tidx};
  for (int hh = 0; hh < 2; hh++) {
    transpose_k<<<dim3(256, 64), 256, 0, stream>>>(Wg[hh], bufT, 2048, 8192, 0);
    gemm_bt<<<dim3(64, 8), 256, 0, stream>>>(hn, 2048, idx[hh], bufT, 2048, nullptr,
                                             g, nullptr, 8192, 3, nullptr, nullptr);
    transpose_k<<<dim3(256, 64), 256, 0, stream>>>(Wu[hh], bufT, 2048, 8192, 0);
    gemm_bt<<<dim3(64, 8), 256, 0, stream>>>(hn, 2048, idx[hh], bufT, 2048, nullptr,
                                             act, nullptr, 8192, 2, g, nullptr);
    transpose_k<<<dim3(64, 256), 256, 0, stream>>>(Wd[hh], bufT, 8192, 2048, 0);
    gemm_bt<<<dim3(16, 8), 256, 0, stream>>>(act, 8192, nullptr, bufT, 8192, out0,
                                             nullptr, idx[hh], 2048, 0, nullptr,
                                             nullptr);
  }
}

// Round 3
// 1365.611 us; speedup vs baseline: 2.4619x; 1.0167x over previous
//
#include <hip/hip_runtime.h>

// InternLM2VE decoder layer, MI355X gfx950.
// R6 == R5 resubmit (R5 bench died on container infra, no counters).
// gemm_bt staging via __builtin_amdgcn_global_load_lds width=16 (m97
// structure: pre-swizzled global source + linear LDS dest + swizzled
// fragment reads).  Attention (R4 MFMA flash) and all else unchanged.
// H=2048, NH=16, NKV=8, HD=128, S=2048, FF=8192, B=1.
// d_out (f32) = [ out (2048x2048) | residual (2048x2048) ].

typedef __bf16 bf16_t;
typedef __bf16 bf16x8 __attribute__((ext_vector_type(8)));
typedef float f32x4 __attribute__((ext_vector_type(4)));

// global ptr -> as(1) via integer round-trip (same representation on gfx9);
// LDS ptr -> as(3) via addrspacecast (strips the flat aperture).
#define GLOAD16(gp, lp)                                                     \
  __builtin_amdgcn_global_load_lds(                                         \
      (__attribute__((address_space(1))) void*)(unsigned long long)(gp),    \
      (__attribute__((address_space(3))) void*)(lp), 16, 0, 0)

// ---------------------------------------------------------------------------
// Tiled transpose + cast f32->bf16: Wt[row_off+n][k] = W[k][n].
// ---------------------------------------------------------------------------
__global__ __launch_bounds__(256) void transpose_k(const float* __restrict__ W,
                                                   bf16_t* __restrict__ Wt,
                                                   int K, int N, int row_off) {
  __shared__ bf16_t tile[32][34];  // stride 68B: no pow-2 bank aliasing
  const int tx = threadIdx.x & 31, ty = threadIdx.x >> 5;
  const int n0 = blockIdx.x * 32, k0 = blockIdx.y * 32;
#pragma unroll
  for (int i = 0; i < 4; i++)
    tile[ty + 8 * i][tx] = (bf16_t)W[(size_t)(k0 + ty + 8 * i) * N + n0 + tx];
  __syncthreads();
#pragma unroll
  for (int i = 0; i < 4; i++)
    Wt[(size_t)(row_off + n0 + ty + 8 * i) * K + k0 + tx] = tile[tx][ty + 8 * i];
}

// ---------------------------------------------------------------------------
// bf16 -> bf16 tiled transpose: out[c][r] = in[r][c].  Used to pre-transpose
// the V slice of qkvb ([s][d], ld 4096) into vt [1024 d][2048 s].
// ---------------------------------------------------------------------------
__global__ __launch_bounds__(256) void transpose_bf16_k(
    const bf16_t* __restrict__ in, int ldin, bf16_t* __restrict__ out, int ldout) {
  __shared__ bf16_t tile[32][34];
  const int tx = threadIdx.x & 31, ty = threadIdx.x >> 5;
  const int c0 = blockIdx.x * 32, r0 = blockIdx.y * 32;
#pragma unroll
  for (int i = 0; i < 4; i++)
    tile[ty + 8 * i][tx] = in[(size_t)(r0 + ty + 8 * i) * ldin + c0 + tx];
  __syncthreads();
#pragma unroll
  for (int i = 0; i < 4; i++)
    out[(size_t)(c0 + ty + 8 * i) * ldout + r0 + tx] = tile[tx][ty + 8 * i];
}

// ---------------------------------------------------------------------------
// RMSNorm row: y = bf16( x * rsqrt(mean(x^2)+eps) * w )   (f32 in, bf16 out)
// ---------------------------------------------------------------------------
__global__ __launch_bounds__(256) void rmsnorm_k(const float* __restrict__ x,
                                                 const float* __restrict__ w,
                                                 bf16_t* __restrict__ y) {
  const int row = blockIdx.x, t = threadIdx.x;
  __shared__ float red[256];
  float vals[8];
  float ss = 0.f;
  const float* xr = x + (size_t)row * 2048;
#pragma unroll
  for (int i = 0; i < 8; i++) {
    float v = xr[t + 256 * i];
    vals[i] = v;
    ss += v * v;
  }
  red[t] = ss;
  __syncthreads();
  for (int s = 128; s > 0; s >>= 1) {
    if (t < s) red[t] += red[t + s];
    __syncthreads();
  }
  const float scale = rsqrtf(red[0] * (1.f / 2048.f) + 1e-6f);
  bf16_t* yr = y + (size_t)row * 2048;
#pragma unroll
  for (int i = 0; i < 8; i++)
    yr[t + 256 * i] = (bf16_t)(vals[i] * scale * w[t + 256 * i]);
}

// ---------------------------------------------------------------------------
// RoPE in-place on bf16 qkv buffer (row = 4096: q[16*128] | k[8*128] | v).
// grid (S, 24): heads 0..15 = q, 16..23 = k (offset head*128 covers both).
// ---------------------------------------------------------------------------
__global__ __launch_bounds__(128) void rope_k(bf16_t* __restrict__ qkv,
                                              const float* __restrict__ cosb,
                                              const float* __restrict__ sinb) {
  const int s = blockIdx.x, head = blockIdx.y, d = threadIdx.x;
  bf16_t* p = qkv + (size_t)s * 4096 + head * 128;
  const float x = (float)p[d];
  const float partner = (float)p[d ^ 64];
  const float rot = (d < 64) ? -partner : partner;
  const float c = cosb[s * 128 + d], sn = sinb[s * 128 + d];
  __syncthreads();  // head is block-uniform; all reads before in-place writes
  p[d] = (bf16_t)(x * c + rot * sn);
}

// ---------------------------------------------------------------------------
// MFMA flash attention, causal GQA.  Grid (S/64 = 32 q-tiles, NH = 16).
// 256 threads = 4 waves; wave w owns q rows [q0+16w, q0+16w+16).
// (unchanged from R4)
// ---------------------------------------------------------------------------
__global__ __launch_bounds__(256) void attn_mfma_k(
    const bf16_t* __restrict__ qkv,  // [S][4096]: q | k (roped) | v
    const bf16_t* __restrict__ vt,   // [1024][2048]: V transposed (d-major)
    bf16_t* __restrict__ ob) {       // [S][2048]
  __shared__ __align__(16) bf16_t Ks[64][136];   // k x c  (pad 128->136)
  __shared__ __align__(16) bf16_t Vs[128][72];   // d x k  (pad 64->72)
  __shared__ __align__(16) bf16_t Ps[4][16][72]; // per-wave P scratch

  const int t = threadIdx.x;
  const int wid = t >> 6, lane = t & 63;
  const int lr = lane & 15, lg = lane >> 4;
  const int h = blockIdx.y, kvh = h >> 1;
  // heavy q-tiles first (in-order dispatch -> better tail balance)
  const int qt = (int)gridDim.x - 1 - (int)blockIdx.x;
  const int q0 = qt * 64;
  const int nkb = qt + 1;
  const int qrow_base = q0 + wid * 16;

  // Q fragment: lane holds Q[lr][lg*8 + 32*cs + j], j=0..7
  bf16x8 qf[4];
#pragma unroll
  for (int cs = 0; cs < 4; ++cs)
    qf[cs] = *(const bf16x8*)(qkv + (size_t)(qrow_base + lr) * 4096 + h * 128 +
                              lg * 8 + 32 * cs);

  f32x4 acc[8];
#pragma unroll
  for (int dt = 0; dt < 8; ++dt) acc[dt] = f32x4{0.f, 0.f, 0.f, 0.f};
  float m_run[4] = {-1e30f, -1e30f, -1e30f, -1e30f};
  float l_run[4] = {0.f, 0.f, 0.f, 0.f};

  const float SCALE = 0.08838834764831845f;  // 1/sqrt(128)

  for (int kb = 0; kb < nkb; ++kb) {
    const int k0 = kb * 64;
    __syncthreads();  // previous iteration's fragment reads complete
    // stage K tile: 64 rows x 128 c, 1024 bf16x8 vectors, 4 per thread
#pragma unroll
    for (int i = 0; i < 4; ++i) {
      const int v = t + 256 * i;
      const int kr = v >> 4, c = (v & 15) * 8;
      *(bf16x8*)&Ks[kr][c] =
          *(const bf16x8*)(qkv + (size_t)(k0 + kr) * 4096 + 2048 + kvh * 128 + c);
    }
    // stage Vt tile: 128 d-rows x 64 k, from pre-transposed vt (coalesced)
#pragma unroll
    for (int i = 0; i < 4; ++i) {
      const int v = t + 256 * i;
      const int d = v >> 3, kk = (v & 7) * 8;
      *(bf16x8*)&Vs[d][kk] =
          *(const bf16x8*)(vt + (size_t)(kvh * 128 + d) * 2048 + k0 + kk);
    }
    __syncthreads();

    // QK^T: S[q][k] tile 16x64; D layout: lane's sv[t4][r] = S[4*lg+r][16*t4+lr]
    f32x4 sv[4];
#pragma unroll
    for (int t4 = 0; t4 < 4; ++t4) sv[t4] = f32x4{0.f, 0.f, 0.f, 0.f};
#pragma unroll
    for (int cs = 0; cs < 4; ++cs) {
#pragma unroll
      for (int t4 = 0; t4 < 4; ++t4) {
        const bf16x8 kf = *(const bf16x8*)&Ks[16 * t4 + lr][lg * 8 + 32 * cs];
        sv[t4] = __builtin_amdgcn_mfma_f32_16x16x32_bf16(qf[cs], kf, sv[t4], 0, 0, 0);
      }
    }

    // scale + causal mask (only final k-block triggers)
    const bool need_mask = (k0 + 63) > qrow_base;
#pragma unroll
    for (int t4 = 0; t4 < 4; ++t4) {
#pragma unroll
      for (int r = 0; r < 4; ++r) {
        float x = sv[t4][r] * SCALE;
        if (need_mask && (k0 + 16 * t4 + lr) > (qrow_base + 4 * lg + r)) x = -1e30f;
        sv[t4][r] = x;
      }
    }

    // online softmax, per q-row r (row owned by the 16 lanes sharing lg)
#pragma unroll
    for (int r = 0; r < 4; ++r) {
      float mx = fmaxf(fmaxf(sv[0][r], sv[1][r]), fmaxf(sv[2][r], sv[3][r]));
      mx = fmaxf(mx, __shfl_xor(mx, 1));
      mx = fmaxf(mx, __shfl_xor(mx, 2));
      mx = fmaxf(mx, __shfl_xor(mx, 4));
      mx = fmaxf(mx, __shfl_xor(mx, 8));
      const float mnew = fmaxf(m_run[r], mx);
      const float corr = __expf(m_run[r] - mnew);
      m_run[r] = mnew;
      float ls = 0.f;
#pragma unroll
      for (int t4 = 0; t4 < 4; ++t4) {
        const float p = __expf(sv[t4][r] - mnew);
        ls += p;
        Ps[wid][4 * lg + r][16 * t4 + lr] = (bf16_t)p;
      }
      ls += __shfl_xor(ls, 1);
      ls += __shfl_xor(ls, 2);
      ls += __shfl_xor(ls, 4);
      ls += __shfl_xor(ls, 8);
      l_run[r] = l_run[r] * corr + ls;
#pragma unroll
      for (int dt = 0; dt < 8; ++dt) acc[dt][r] *= corr;
    }

    // PV: O[q][d] += P[q][k] V[k][d].  A-frag re-read from Ps (wave-private,
    // compiler orders the intra-wave LDS write->read).
#pragma unroll
    for (int ks = 0; ks < 2; ++ks) {
      const bf16x8 pa = *(const bf16x8*)&Ps[wid][lr][lg * 8 + 32 * ks];
#pragma unroll
      for (int dt = 0; dt < 8; ++dt) {
        const bf16x8 vf = *(const bf16x8*)&Vs[16 * dt + lr][lg * 8 + 32 * ks];
        acc[dt] = __builtin_amdgcn_mfma_f32_16x16x32_bf16(pa, vf, acc[dt], 0, 0, 0);
      }
    }
  }

  // epilogue: normalize and store; lane's acc[dt][r] = O[4*lg+r][16*dt+lr]
#pragma unroll
  for (int r = 0; r < 4; ++r) {
    const float inv = 1.f / l_run[r];
    const size_t row = (size_t)(qrow_base + 4 * lg + r) * 2048 + h * 128;
#pragma unroll
    for (int dt = 0; dt < 8; ++dt)
      ob[row + 16 * dt + lr] = (bf16_t)(acc[dt][r] * inv);
  }
}

// ---------------------------------------------------------------------------
// bf16 MFMA GEMM: C[M,N] = A[M,K] @ Bt[N,K]^T, 128x128 tile, BK=32, 4 waves.
// Staging via global_load_lds width=16 (direct HBM->LDS, no VGPR trip).
// LDS dest is LINEAR in lane order (HW requirement); bank conflicts avoided
// by pre-swizzling the per-lane GLOBAL source k-chunk (XOR) and applying the
// matching XOR on the fragment ds_read side (rule #21: both-sides-or-neither).
// A rows gathered via a_idx; C rows scattered via c_idx (both optional).
// mode 0: Cf = acc                        [down proj -> f32 out]
// mode 1: Cf = acc + Rf                   [o-proj + residual, f32]
// mode 2: Cb = bf16(silu(Gb) * acc)       [SwiGLU up fuse]
// mode 3: Cb = bf16(acc)                  [QKV, gate]
// ---------------------------------------------------------------------------
__global__ __launch_bounds__(256) void gemm_bt(
    const bf16_t* __restrict__ A, int lda, const int* __restrict__ a_idx,
    const bf16_t* __restrict__ Bt, int K,
    float* __restrict__ Cf, bf16_t* __restrict__ Cb,
    const int* __restrict__ c_idx, int ldc, int mode,
    const bf16_t* __restrict__ Gb, const float* __restrict__ Rf) {
  __shared__ __align__(16) bf16_t As[128 * 32];
  __shared__ __align__(16) bf16_t Bs[128 * 32];
  __shared__ int arows[128];

  const int t = threadIdx.x;
  const int row0 = blockIdx.y * 128, col0 = blockIdx.x * 128;

  if (t < 128) arows[t] = a_idx ? a_idx[row0 + t] : (row0 + t);
  __syncthreads();

  // 512 16B segments per 128x32 tile; seg = p*256+t; m=seg>>2; LDS slot
  // c=seg&3 holds global k-chunk q = c ^ ((m>>1)&3)   (bank swizzle)
  const int sm0 = t >> 2;
  const int sq0 = (((t & 3) ^ ((sm0 >> 1) & 3)) << 3);
  const int sm1 = (t + 256) >> 2;
  const int sq1 = ((((t + 256) & 3) ^ ((sm1 >> 1) & 3)) << 3);

  const bf16_t* gA0 = A + (size_t)arows[sm0] * lda + sq0;
  const bf16_t* gA1 = A + (size_t)arows[sm1] * lda + sq1;
  const bf16_t* gB0 = Bt + (size_t)(col0 + sm0) * K + sq0;
  const bf16_t* gB1 = Bt + (size_t)(col0 + sm1) * K + sq1;

  const int wid = t >> 6, lane = t & 63;
  // wave-uniform LDS bases: seg (64*wid + lane) at elem offset wid*512+lane*8;
  // HW adds lane*16B, so base = wid*512 elems.  Slot1 = +2048 elems.
  bf16_t* ldsA0 = As + wid * 512;
  bf16_t* ldsA1 = As + 2048 + wid * 512;
  bf16_t* ldsB0 = Bs + wid * 512;
  bf16_t* ldsB1 = Bs + 2048 + wid * 512;

  const int wm = (wid & 1) << 6, wn = (wid >> 1) << 6;
  const int lrow = lane & 15, lq = lane >> 4;

  int a_off[4], b_off[4];
#pragma unroll
  for (int i = 0; i < 4; i++) {
    const int m = wm + i * 16 + lrow;
    a_off[i] = m * 64 + ((lq ^ ((m >> 1) & 3)) << 4);  // bytes
    const int n = wn + i * 16 + lrow;
    b_off[i] = n * 64 + ((lq ^ ((n >> 1) & 3)) << 4);
  }

  f32x4 acc[4][4];
#pragma unroll
  for (int i = 0; i < 4; i++)
#pragma unroll
    for (int j = 0; j < 4; j++) acc[i][j] = f32x4{0.f, 0.f, 0.f, 0.f};

  for (int k0 = 0; k0 < K; k0 += 32) {
    __syncthreads();  // prior iteration's fragment reads complete
    GLOAD16(gA0 + k0, ldsA0);
    GLOAD16(gA1 + k0, ldsA1);
    GLOAD16(gB0 + k0, ldsB0);
    GLOAD16(gB1 + k0, ldsB1);
    __syncthreads();  // vmcnt drained at barrier -> staging visible
    bf16x8 af[4], bfr[4];
#pragma unroll
    for (int i = 0; i < 4; i++)
      af[i] = *(const bf16x8*)((const char*)As + a_off[i]);
#pragma unroll
    for (int i = 0; i < 4; i++)
      bfr[i] = *(const bf16x8*)((const char*)Bs + b_off[i]);
#pragma unroll
    for (int i = 0; i < 4; i++)
#pragma unroll
      for (int j = 0; j < 4; j++)
        acc[i][j] =
            __builtin_amdgcn_mfma_f32_16x16x32_bf16(af[i], bfr[j], acc[i][j], 0, 0, 0);
  }

#pragma unroll
  for (int i = 0; i < 4; i++) {
#pragma unroll
    for (int r = 0; r < 4; r++) {
      const int gm = row0 + wm + i * 16 + lq * 4 + r;  // C/D: row=(lane>>4)*4+r
      const int crow = c_idx ? c_idx[gm] : gm;
      const size_t base = (size_t)crow * ldc;
#pragma unroll
      for (int j = 0; j < 4; j++) {
        const int col = col0 + wn + j * 16 + lrow;  // C/D: col=lane&15
        float v = acc[i][j][r];
        if (mode == 0) {
          Cf[base + col] = v;
        } else if (mode == 1) {
          Cf[base + col] = v + Rf[base + col];
        } else if (mode == 2) {
          const float g = (float)Gb[base + col];
          Cb[base + col] = (bf16_t)(v * g / (1.f + __expf(-g)));
        } else {
          Cb[base + col] = (bf16_t)v;
        }
      }
    }
  }
}

// ---------------------------------------------------------------------------
extern "C" void kernel_launch(void* const* d_in, const int* in_sizes, int n_in,
                              void* d_out, int out_size, void* d_ws, size_t ws_size,
                              hipStream_t stream) {
  const float* hidden = (const float*)d_in[0];
  const float* cosb = (const float*)d_in[1];
  const float* sinb = (const float*)d_in[2];
  const float* wq = (const float*)d_in[3];
  const float* wk = (const float*)d_in[4];
  const float* wv = (const float*)d_in[5];
  const float* wo = (const float*)d_in[6];
  const float* w1 = (const float*)d_in[7];
  const float* w3 = (const float*)d_in[8];
  const float* w2 = (const float*)d_in[9];
  const float* v1 = (const float*)d_in[10];
  const float* v3 = (const float*)d_in[11];
  const float* v2 = (const float*)d_in[12];
  const float* anw = (const float*)d_in[13];
  const float* fnw = (const float*)d_in[14];
  const int* vidx = (const int*)d_in[15];
  const int* tidx = (const int*)d_in[16];

  float* out0 = (float*)d_out;                // MLP output [2048][2048] f32
  float* outr = out0 + (size_t)2048 * 2048;   // residual   [2048][2048] f32

  // ws layout (72 MB), all bf16 intermediates; offsets in MB
  char* wsb = (char*)d_ws;
  const size_t MB = 1024 * 1024;
  bf16_t* qkvb = (bf16_t*)(wsb + 0 * MB);    // [0,16): QKV out, q/k roped in place
  bf16_t* vt = (bf16_t*)(wsb + 16 * MB);     // [16,20): V transposed [1024][2048]
  bf16_t* attnb = (bf16_t*)(wsb + 24 * MB);  // [24,32)
  bf16_t* hn = (bf16_t*)(wsb + 32 * MB);     // [32,40): norm out (attn, then ffn)
  bf16_t* g = (bf16_t*)(wsb + 0 * MB);       // [0,16): gate (qkvb dead)
  bf16_t* act = (bf16_t*)(wsb + 16 * MB);    // [16,32): silu*up (vt/attnb dead)
  bf16_t* bufT = (bf16_t*)(wsb + 40 * MB);   // [40,72): transposed bf16 weights

  // --- attention block ---
  transpose_k<<<dim3(64, 64), 256, 0, stream>>>(wq, bufT, 2048, 2048, 0);
  transpose_k<<<dim3(32, 64), 256, 0, stream>>>(wk, bufT, 2048, 1024, 2048);
  transpose_k<<<dim3(32, 64), 256, 0, stream>>>(wv, bufT, 2048, 1024, 3072);
  rmsnorm_k<<<2048, 256, 0, stream>>>(hidden, anw, hn);
  gemm_bt<<<dim3(32, 16), 256, 0, stream>>>(hn, 2048, nullptr, bufT, 2048, nullptr,
                                            qkvb, nullptr, 4096, 3, nullptr, nullptr);
  rope_k<<<dim3(2048, 24), 128, 0, stream>>>(qkvb, cosb, sinb);
  transpose_bf16_k<<<dim3(32, 64), 256, 0, stream>>>(qkvb + 3072, 4096, vt, 2048);
  attn_mfma_k<<<dim3(32, 16), 256, 0, stream>>>(qkvb, vt, attnb);
  transpose_k<<<dim3(64, 64), 256, 0, stream>>>(wo, bufT, 2048, 2048, 0);
  gemm_bt<<<dim3(16, 16), 256, 0, stream>>>(attnb, 2048, nullptr, bufT, 2048, outr,
                                            nullptr, nullptr, 2048, 1, nullptr, hidden);
  // --- FFN block (residual re-read f32 from d_out; vision rows, then text) ---
  rmsnorm_k<<<2048, 256, 0, stream>>>(outr, fnw, hn);
  const float* Wg[2] = {v1, w1};
  const float* Wu[2] = {v3, w3};
  const float* Wd[2] = {v2, w2};
  const int* idx[2] = {vidx, tidx};
  for (int hh = 0; hh < 2; hh++) {
    transpose_k<<<dim3(256, 64), 256, 0, stream>>>(Wg[hh], bufT, 2048, 8192, 0);
    gemm_bt<<<dim3(64, 8), 256, 0, stream>>>(hn, 2048, idx[hh], bufT, 2048, nullptr,
                                             g, nullptr, 8192, 3, nullptr, nullptr);
    transpose_k<<<dim3(256, 64), 256, 0, stream>>>(Wu[hh], bufT, 2048, 8192, 0);
    gemm_bt<<<dim3(64, 8), 256, 0, stream>>>(hn, 2048, idx[hh], bufT, 2048, nullptr,
                                             act, nullptr, 8192, 2, g, nullptr);
    transpose_k<<<dim3(64, 256), 256, 0, stream>>>(Wd[hh], bufT, 8192, 2048, 0);
    gemm_bt<<<dim3(16, 8), 256, 0, stream>>>(act, 8192, nullptr, bufT, 8192, out0,
                                             nullptr, idx[hh], 2048, 0, nullptr,
                                             nullptr);
  }
}

// Round 4
// 1193.336 us; speedup vs baseline: 2.8173x; 1.1444x over previous
//
#include <hip/hip_runtime.h>

// InternLM2VE decoder layer, MI355X gfx950.
// R7: occupancy-first GEMM restructure. 128x64 tiles (was 128x128) + split-K
// (atomicAdd f32 epilogue) so EVERY gemm dispatch is 1024 blocks = 4/CU
// (was 2/CU, down-proj 0.5/CU; OccupancyPercent 5.8%, MfmaUtil 7%).
// Residual via outr:=hidden copy + o-proj atomicAdd; out0 zeroed before
// down-proj atomics. Gate buffer lives in out0's region until then.
// H=2048, NH=16, NKV=8, HD=128, S=2048, FF=8192, B=1.
// d_out (f32) = [ out (2048x2048) | residual (2048x2048) ].

typedef __bf16 bf16_t;
typedef __bf16 bf16x8 __attribute__((ext_vector_type(8)));
typedef float f32x4 __attribute__((ext_vector_type(4)));

#define GLOAD16(gp, lp)                                                     \
  __builtin_amdgcn_global_load_lds(                                         \
      (__attribute__((address_space(1))) void*)(unsigned long long)(gp),    \
      (__attribute__((address_space(3))) void*)(lp), 16, 0, 0)

// ---------------------------------------------------------------------------
// Tiled transpose + cast f32->bf16: Wt[row_off+n][k] = W[k][n].
// ---------------------------------------------------------------------------
__global__ __launch_bounds__(256) void transpose_k(const float* __restrict__ W,
                                                   bf16_t* __restrict__ Wt,
                                                   int K, int N, int row_off) {
  __shared__ bf16_t tile[32][34];  // stride 68B: no pow-2 bank aliasing
  const int tx = threadIdx.x & 31, ty = threadIdx.x >> 5;
  const int n0 = blockIdx.x * 32, k0 = blockIdx.y * 32;
#pragma unroll
  for (int i = 0; i < 4; i++)
    tile[ty + 8 * i][tx] = (bf16_t)W[(size_t)(k0 + ty + 8 * i) * N + n0 + tx];
  __syncthreads();
#pragma unroll
  for (int i = 0; i < 4; i++)
    Wt[(size_t)(row_off + n0 + ty + 8 * i) * K + k0 + tx] = tile[tx][ty + 8 * i];
}

// ---------------------------------------------------------------------------
// bf16 -> bf16 tiled transpose (V slice of qkvb -> vt [1024 d][2048 s]).
// ---------------------------------------------------------------------------
__global__ __launch_bounds__(256) void transpose_bf16_k(
    const bf16_t* __restrict__ in, int ldin, bf16_t* __restrict__ out, int ldout) {
  __shared__ bf16_t tile[32][34];
  const int tx = threadIdx.x & 31, ty = threadIdx.x >> 5;
  const int c0 = blockIdx.x * 32, r0 = blockIdx.y * 32;
#pragma unroll
  for (int i = 0; i < 4; i++)
    tile[ty + 8 * i][tx] = in[(size_t)(r0 + ty + 8 * i) * ldin + c0 + tx];
  __syncthreads();
#pragma unroll
  for (int i = 0; i < 4; i++)
    out[(size_t)(c0 + ty + 8 * i) * ldout + r0 + tx] = tile[tx][ty + 8 * i];
}

// ---------------------------------------------------------------------------
// f32 copy / zero (float4 grid-stride).  n = count of float4.
// ---------------------------------------------------------------------------
__global__ __launch_bounds__(256) void fcopy_k(const float4* __restrict__ s,
                                               float4* __restrict__ d, int n) {
  for (int i = blockIdx.x * 256 + threadIdx.x; i < n; i += gridDim.x * 256)
    d[i] = s[i];
}
__global__ __launch_bounds__(256) void fzero_k(float4* __restrict__ d, int n) {
  const float4 z = {0.f, 0.f, 0.f, 0.f};
  for (int i = blockIdx.x * 256 + threadIdx.x; i < n; i += gridDim.x * 256)
    d[i] = z;
}

// ---------------------------------------------------------------------------
// RMSNorm row: y = bf16( x * rsqrt(mean(x^2)+eps) * w )   (f32 in, bf16 out)
// ---------------------------------------------------------------------------
__global__ __launch_bounds__(256) void rmsnorm_k(const float* __restrict__ x,
                                                 const float* __restrict__ w,
                                                 bf16_t* __restrict__ y) {
  const int row = blockIdx.x, t = threadIdx.x;
  __shared__ float red[256];
  float vals[8];
  float ss = 0.f;
  const float* xr = x + (size_t)row * 2048;
#pragma unroll
  for (int i = 0; i < 8; i++) {
    float v = xr[t + 256 * i];
    vals[i] = v;
    ss += v * v;
  }
  red[t] = ss;
  __syncthreads();
  for (int s = 128; s > 0; s >>= 1) {
    if (t < s) red[t] += red[t + s];
    __syncthreads();
  }
  const float scale = rsqrtf(red[0] * (1.f / 2048.f) + 1e-6f);
  bf16_t* yr = y + (size_t)row * 2048;
#pragma unroll
  for (int i = 0; i < 8; i++)
    yr[t + 256 * i] = (bf16_t)(vals[i] * scale * w[t + 256 * i]);
}

// ---------------------------------------------------------------------------
// RoPE in-place on bf16 qkv buffer (row = 4096: q[16*128] | k[8*128] | v).
// grid (S, 24): heads 0..15 = q, 16..23 = k.
// ---------------------------------------------------------------------------
__global__ __launch_bounds__(128) void rope_k(bf16_t* __restrict__ qkv,
                                              const float* __restrict__ cosb,
                                              const float* __restrict__ sinb) {
  const int s = blockIdx.x, head = blockIdx.y, d = threadIdx.x;
  bf16_t* p = qkv + (size_t)s * 4096 + head * 128;
  const float x = (float)p[d];
  const float partner = (float)p[d ^ 64];
  const float rot = (d < 64) ? -partner : partner;
  const float c = cosb[s * 128 + d], sn = sinb[s * 128 + d];
  __syncthreads();  // head is block-uniform; all reads before in-place writes
  p[d] = (bf16_t)(x * c + rot * sn);
}

// ---------------------------------------------------------------------------
// MFMA flash attention, causal GQA (unchanged from R4).
// ---------------------------------------------------------------------------
__global__ __launch_bounds__(256) void attn_mfma_k(
    const bf16_t* __restrict__ qkv,  // [S][4096]: q | k (roped) | v
    const bf16_t* __restrict__ vt,   // [1024][2048]: V transposed (d-major)
    bf16_t* __restrict__ ob) {       // [S][2048]
  __shared__ __align__(16) bf16_t Ks[64][136];   // k x c  (pad 128->136)
  __shared__ __align__(16) bf16_t Vs[128][72];   // d x k  (pad 64->72)
  __shared__ __align__(16) bf16_t Ps[4][16][72]; // per-wave P scratch

  const int t = threadIdx.x;
  const int wid = t >> 6, lane = t & 63;
  const int lr = lane & 15, lg = lane >> 4;
  const int h = blockIdx.y, kvh = h >> 1;
  const int qt = (int)gridDim.x - 1 - (int)blockIdx.x;
  const int q0 = qt * 64;
  const int nkb = qt + 1;
  const int qrow_base = q0 + wid * 16;

  bf16x8 qf[4];
#pragma unroll
  for (int cs = 0; cs < 4; ++cs)
    qf[cs] = *(const bf16x8*)(qkv + (size_t)(qrow_base + lr) * 4096 + h * 128 +
                              lg * 8 + 32 * cs);

  f32x4 acc[8];
#pragma unroll
  for (int dt = 0; dt < 8; ++dt) acc[dt] = f32x4{0.f, 0.f, 0.f, 0.f};
  float m_run[4] = {-1e30f, -1e30f, -1e30f, -1e30f};
  float l_run[4] = {0.f, 0.f, 0.f, 0.f};

  const float SCALE = 0.08838834764831845f;  // 1/sqrt(128)

  for (int kb = 0; kb < nkb; ++kb) {
    const int k0 = kb * 64;
    __syncthreads();
#pragma unroll
    for (int i = 0; i < 4; ++i) {
      const int v = t + 256 * i;
      const int kr = v >> 4, c = (v & 15) * 8;
      *(bf16x8*)&Ks[kr][c] =
          *(const bf16x8*)(qkv + (size_t)(k0 + kr) * 4096 + 2048 + kvh * 128 + c);
    }
#pragma unroll
    for (int i = 0; i < 4; ++i) {
      const int v = t + 256 * i;
      const int d = v >> 3, kk = (v & 7) * 8;
      *(bf16x8*)&Vs[d][kk] =
          *(const bf16x8*)(vt + (size_t)(kvh * 128 + d) * 2048 + k0 + kk);
    }
    __syncthreads();

    f32x4 sv[4];
#pragma unroll
    for (int t4 = 0; t4 < 4; ++t4) sv[t4] = f32x4{0.f, 0.f, 0.f, 0.f};
#pragma unroll
    for (int cs = 0; cs < 4; ++cs) {
#pragma unroll
      for (int t4 = 0; t4 < 4; ++t4) {
        const bf16x8 kf = *(const bf16x8*)&Ks[16 * t4 + lr][lg * 8 + 32 * cs];
        sv[t4] = __builtin_amdgcn_mfma_f32_16x16x32_bf16(qf[cs], kf, sv[t4], 0, 0, 0);
      }
    }

    const bool need_mask = (k0 + 63) > qrow_base;
#pragma unroll
    for (int t4 = 0; t4 < 4; ++t4) {
#pragma unroll
      for (int r = 0; r < 4; ++r) {
        float x = sv[t4][r] * SCALE;
        if (need_mask && (k0 + 16 * t4 + lr) > (qrow_base + 4 * lg + r)) x = -1e30f;
        sv[t4][r] = x;
      }
    }

#pragma unroll
    for (int r = 0; r < 4; ++r) {
      float mx = fmaxf(fmaxf(sv[0][r], sv[1][r]), fmaxf(sv[2][r], sv[3][r]));
      mx = fmaxf(mx, __shfl_xor(mx, 1));
      mx = fmaxf(mx, __shfl_xor(mx, 2));
      mx = fmaxf(mx, __shfl_xor(mx, 4));
      mx = fmaxf(mx, __shfl_xor(mx, 8));
      const float mnew = fmaxf(m_run[r], mx);
      const float corr = __expf(m_run[r] - mnew);
      m_run[r] = mnew;
      float ls = 0.f;
#pragma unroll
      for (int t4 = 0; t4 < 4; ++t4) {
        const float p = __expf(sv[t4][r] - mnew);
        ls += p;
        Ps[wid][4 * lg + r][16 * t4 + lr] = (bf16_t)p;
      }
      ls += __shfl_xor(ls, 1);
      ls += __shfl_xor(ls, 2);
      ls += __shfl_xor(ls, 4);
      ls += __shfl_xor(ls, 8);
      l_run[r] = l_run[r] * corr + ls;
#pragma unroll
      for (int dt = 0; dt < 8; ++dt) acc[dt][r] *= corr;
    }

#pragma unroll
    for (int ks = 0; ks < 2; ++ks) {
      const bf16x8 pa = *(const bf16x8*)&Ps[wid][lr][lg * 8 + 32 * ks];
#pragma unroll
      for (int dt = 0; dt < 8; ++dt) {
        const bf16x8 vf = *(const bf16x8*)&Vs[16 * dt + lr][lg * 8 + 32 * ks];
        acc[dt] = __builtin_amdgcn_mfma_f32_16x16x32_bf16(pa, vf, acc[dt], 0, 0, 0);
      }
    }
  }

#pragma unroll
  for (int r = 0; r < 4; ++r) {
    const float inv = 1.f / l_run[r];
    const size_t row = (size_t)(qrow_base + 4 * lg + r) * 2048 + h * 128;
#pragma unroll
    for (int dt = 0; dt < 8; ++dt)
      ob[row + 16 * dt + lr] = (bf16_t)(acc[dt][r] * inv);
  }
}

// ---------------------------------------------------------------------------
// bf16 MFMA GEMM: C[M,N] = A[M,K] @ Bt[N,K]^T, 128x64 tile, BK=32, 4 waves
// (each wave 64x32 = 4x2 fragments).  Staging via global_load_lds width=16
// with pre-swizzled global source + linear LDS + swizzled fragment reads.
// Split-K via gridDim.z (K/z per slice); f32 modes use atomicAdd.
// A rows gathered via a_idx; C rows scattered via c_idx (both optional).
// mode 0: atomicAdd(Cf, acc)              [o-proj into outr=hidden; down-proj]
// mode 2: Cb = bf16(silu(Gb) * acc)       [SwiGLU up fuse]
// mode 3: Cb = bf16(acc)                  [QKV, gate]
// ---------------------------------------------------------------------------
__global__ __launch_bounds__(256) void gemm_bt(
    const bf16_t* __restrict__ A, int lda, const int* __restrict__ a_idx,
    const bf16_t* __restrict__ Bt, int K,
    float* __restrict__ Cf, bf16_t* __restrict__ Cb,
    const int* __restrict__ c_idx, int ldc, int mode,
    const bf16_t* __restrict__ Gb) {
  __shared__ __align__(16) bf16_t As[128 * 32];
  __shared__ __align__(16) bf16_t Bs[64 * 32];
  __shared__ int arows[128];

  const int t = threadIdx.x;
  const int row0 = blockIdx.y * 128, col0 = blockIdx.x * 64;
  const int kpz = K / (int)gridDim.z;
  const int kbeg = blockIdx.z * kpz, kend = kbeg + kpz;

  if (t < 128) arows[t] = a_idx ? a_idx[row0 + t] : (row0 + t);
  __syncthreads();

  // A tile 128x32: 512 16B segs; seg s -> row m=s>>2, LDS chunk c=s&3 holds
  // global k-chunk q = c ^ ((m>>1)&3).  Thread t handles segs t, t+256.
  const int sm0 = t >> 2;
  const int sq0 = (((t & 3) ^ ((sm0 >> 1) & 3)) << 3);
  const int sm1 = (t + 256) >> 2;
  const int sq1 = ((((t + 256) & 3) ^ ((sm1 >> 1) & 3)) << 3);
  // B tile 64x32: 256 segs; thread t handles seg t.
  const int bn0 = t >> 2;
  const int bq0 = (((t & 3) ^ ((bn0 >> 1) & 3)) << 3);

  const bf16_t* gA0 = A + (size_t)arows[sm0] * lda + sq0;
  const bf16_t* gA1 = A + (size_t)arows[sm1] * lda + sq1;
  const bf16_t* gB0 = Bt + (size_t)(col0 + bn0) * K + bq0;

  const int wid = t >> 6, lane = t & 63;
  // wave-uniform LDS bases (HW adds lane*16B)
  bf16_t* ldsA0 = As + wid * 512;
  bf16_t* ldsA1 = As + 2048 + wid * 512;
  bf16_t* ldsB0 = Bs + wid * 512;

  const int wm = (wid & 1) << 6, wn = (wid >> 1) << 5;
  const int lrow = lane & 15, lq = lane >> 4;

  int a_off[4], b_off[2];
#pragma unroll
  for (int i = 0; i < 4; i++) {
    const int m = wm + i * 16 + lrow;
    a_off[i] = m * 64 + ((lq ^ ((m >> 1) & 3)) << 4);  // bytes
  }
#pragma unroll
  for (int j = 0; j < 2; j++) {
    const int n = wn + j * 16 + lrow;
    b_off[j] = n * 64 + ((lq ^ ((n >> 1) & 3)) << 4);
  }

  f32x4 acc[4][2];
#pragma unroll
  for (int i = 0; i < 4; i++)
#pragma unroll
    for (int j = 0; j < 2; j++) acc[i][j] = f32x4{0.f, 0.f, 0.f, 0.f};

  for (int k0 = kbeg; k0 < kend; k0 += 32) {
    __syncthreads();  // prior iteration's fragment reads complete
    GLOAD16(gA0 + k0, ldsA0);
    GLOAD16(gA1 + k0, ldsA1);
    GLOAD16(gB0 + k0, ldsB0);
    __syncthreads();  // staging visible
    bf16x8 af[4], bfr[2];
#pragma unroll
    for (int i = 0; i < 4; i++)
      af[i] = *(const bf16x8*)((const char*)As + a_off[i]);
#pragma unroll
    for (int j = 0; j < 2; j++)
      bfr[j] = *(const bf16x8*)((const char*)Bs + b_off[j]);
#pragma unroll
    for (int i = 0; i < 4; i++)
#pragma unroll
      for (int j = 0; j < 2; j++)
        acc[i][j] =
            __builtin_amdgcn_mfma_f32_16x16x32_bf16(af[i], bfr[j], acc[i][j], 0, 0, 0);
  }

#pragma unroll
  for (int i = 0; i < 4; i++) {
#pragma unroll
    for (int r = 0; r < 4; r++) {
      const int gm = row0 + wm + i * 16 + lq * 4 + r;  // C/D: row=(lane>>4)*4+r
      const int crow = c_idx ? c_idx[gm] : gm;
      const size_t base = (size_t)crow * ldc;
#pragma unroll
      for (int j = 0; j < 2; j++) {
        const int col = col0 + wn + j * 16 + lrow;  // C/D: col=lane&15
        float v = acc[i][j][r];
        if (mode == 0) {
          atomicAdd(Cf + base + col, v);
        } else if (mode == 2) {
          const float g = (float)Gb[base + col];
          Cb[base + col] = (bf16_t)(v * g / (1.f + __expf(-g)));
        } else {
          Cb[base + col] = (bf16_t)v;
        }
      }
    }
  }
}

// ---------------------------------------------------------------------------
extern "C" void kernel_launch(void* const* d_in, const int* in_sizes, int n_in,
                              void* d_out, int out_size, void* d_ws, size_t ws_size,
                              hipStream_t stream) {
  const float* hidden = (const float*)d_in[0];
  const float* cosb = (const float*)d_in[1];
  const float* sinb = (const float*)d_in[2];
  const float* wq = (const float*)d_in[3];
  const float* wk = (const float*)d_in[4];
  const float* wv = (const float*)d_in[5];
  const float* wo = (const float*)d_in[6];
  const float* w1 = (const float*)d_in[7];
  const float* w3 = (const float*)d_in[8];
  const float* w2 = (const float*)d_in[9];
  const float* v1 = (const float*)d_in[10];
  const float* v3 = (const float*)d_in[11];
  const float* v2 = (const float*)d_in[12];
  const float* anw = (const float*)d_in[13];
  const float* fnw = (const float*)d_in[14];
  const int* vidx = (const int*)d_in[15];
  const int* tidx = (const int*)d_in[16];

  float* out0 = (float*)d_out;                // MLP output [2048][2048] f32
  float* outr = out0 + (size_t)2048 * 2048;   // residual   [2048][2048] f32

  // ws layout (72 MB); offsets in MB
  char* wsb = (char*)d_ws;
  const size_t MB = 1024 * 1024;
  bf16_t* qkvb = (bf16_t*)(wsb + 0 * MB);    // [0,16): QKV out, q/k roped in place
  bf16_t* vt = (bf16_t*)(wsb + 16 * MB);     // [16,20): V transposed [1024][2048]
  bf16_t* attnb = (bf16_t*)(wsb + 24 * MB);  // [24,32)
  bf16_t* hn = (bf16_t*)(wsb + 32 * MB);     // [32,40): norm out (attn, then ffn)
  bf16_t* act = (bf16_t*)(wsb + 0 * MB);     // [0,32): silu*up merged [2048][8192]
  bf16_t* bufT = (bf16_t*)(wsb + 40 * MB);   // [40,72): transposed bf16 weights
  bf16_t* gbuf = (bf16_t*)out0;              // gate [1024][8192] bf16 in out0's
                                             // region (dead until down-proj)

  // --- attention block ---
  fcopy_k<<<2048, 256, 0, stream>>>((const float4*)hidden, (float4*)outr,
                                    2048 * 2048 / 4);  // residual init for o-proj
  transpose_k<<<dim3(64, 64), 256, 0, stream>>>(wq, bufT, 2048, 2048, 0);
  transpose_k<<<dim3(32, 64), 256, 0, stream>>>(wk, bufT, 2048, 1024, 2048);
  transpose_k<<<dim3(32, 64), 256, 0, stream>>>(wv, bufT, 2048, 1024, 3072);
  rmsnorm_k<<<2048, 256, 0, stream>>>(hidden, anw, hn);
  gemm_bt<<<dim3(64, 16, 1), 256, 0, stream>>>(hn, 2048, nullptr, bufT, 2048,
                                               nullptr, qkvb, nullptr, 4096, 3,
                                               nullptr);
  rope_k<<<dim3(2048, 24), 128, 0, stream>>>(qkvb, cosb, sinb);
  transpose_bf16_k<<<dim3(32, 64), 256, 0, stream>>>(qkvb + 3072, 4096, vt, 2048);
  attn_mfma_k<<<dim3(32, 16), 256, 0, stream>>>(qkvb, vt, attnb);
  transpose_k<<<dim3(64, 64), 256, 0, stream>>>(wo, bufT, 2048, 2048, 0);
  // o-proj: split-K=2, atomicAdd onto outr (= hidden residual)
  gemm_bt<<<dim3(32, 16, 2), 256, 0, stream>>>(attnb, 2048, nullptr, bufT, 2048,
                                               outr, nullptr, nullptr, 2048, 0,
                                               nullptr);
  // --- FFN block ---
  rmsnorm_k<<<2048, 256, 0, stream>>>(outr, fnw, hn);
  const float* Wg[2] = {v1, w1};
  const float* Wu[2] = {v3, w3};
  const float* Wd[2] = {v2, w2};
  const int* idx[2] = {vidx, tidx};
  for (int hh = 0; hh < 2; hh++) {  // gate+up per half; act rows stacked
    transpose_k<<<dim3(256, 64), 256, 0, stream>>>(Wg[hh], bufT, 2048, 8192, 0);
    gemm_bt<<<dim3(128, 8, 1), 256, 0, stream>>>(hn, 2048, idx[hh], bufT, 2048,
                                                 nullptr, gbuf, nullptr, 8192, 3,
                                                 nullptr);
    transpose_k<<<dim3(256, 64), 256, 0, stream>>>(Wu[hh], bufT, 2048, 8192, 0);
    gemm_bt<<<dim3(128, 8, 1), 256, 0, stream>>>(
        hn, 2048, idx[hh], bufT, 2048, nullptr, act + (size_t)hh * 1024 * 8192,
        nullptr, 8192, 2, gbuf);
  }
  // gbuf (in out0) now dead -> zero out0, then down-proj atomics (split-K=4)
  fzero_k<<<2048, 256, 0, stream>>>((float4*)out0, 2048 * 2048 / 4);
  for (int hh = 0; hh < 2; hh++) {
    transpose_k<<<dim3(64, 256), 256, 0, stream>>>(Wd[hh], bufT, 8192, 2048, 0);
    gemm_bt<<<dim3(32, 8, 4), 256, 0, stream>>>(
        act + (size_t)hh * 1024 * 8192, 8192, nullptr, bufT, 8192, out0, nullptr,
        idx[hh], 2048, 0, nullptr);
  }
}